// Round 6
// baseline (666.879 us; speedup 1.0000x reference)
//
#include <hip/hip_runtime.h>
#include <hip/hip_bf16.h>
#include <cstdint>

#define NODES  65536
#define CH     128
#define NGRAPH 1024
#define PGRAPH 64
#define FCO    65536

typedef __bf16 bf16x8 __attribute__((ext_vector_type(8)));
typedef float  f32x4  __attribute__((ext_vector_type(4)));

// ---------------- graph preprocessing ----------------

__global__ void k_degree(const int* __restrict__ dst, int* __restrict__ deg, int E){
  int e = blockIdx.x*256 + threadIdx.x;
  if (e < E) atomicAdd(&deg[dst[e]], 1);
}

__global__ void k_dinv(const int* __restrict__ deg, float* __restrict__ dinv){
  int i = blockIdx.x*256 + threadIdx.x;
  dinv[i] = 1.0f / sqrtf((float)(deg[i] + 1));   // self-loop -> deg+1 >= 1
}

__global__ void k_scan1(const int* __restrict__ deg, int* __restrict__ excl,
                        int* __restrict__ bsums){
  __shared__ int tmp[256];
  const int t = threadIdx.x;
  const int gid = blockIdx.x*256 + t;
  const int v = deg[gid];
  tmp[t] = v;
  __syncthreads();
  #pragma unroll
  for (int off = 1; off < 256; off <<= 1){
    int x = (t >= off) ? tmp[t-off] : 0;
    __syncthreads();
    tmp[t] += x;
    __syncthreads();
  }
  excl[gid] = tmp[t] - v;
  if (t == 255) bsums[blockIdx.x] = tmp[255];
}

__global__ void k_scan2(int* __restrict__ bsums){
  __shared__ int tmp[256];
  const int t = threadIdx.x;
  const int v = bsums[t];
  tmp[t] = v;
  __syncthreads();
  #pragma unroll
  for (int off = 1; off < 256; off <<= 1){
    int x = (t >= off) ? tmp[t-off] : 0;
    __syncthreads();
    tmp[t] += x;
    __syncthreads();
  }
  bsums[t] = tmp[t] - v;   // exclusive
}

__global__ void k_scan3(int* __restrict__ cstart, const int* __restrict__ bsums, int E){
  const int gid = blockIdx.x*256 + threadIdx.x;
  cstart[gid] += bsums[blockIdx.x];
  if (gid == 0) cstart[NODES] = E;
}

__global__ void k_scatter(const int* __restrict__ src, const int* __restrict__ dst,
                          const int* __restrict__ cstart, int* __restrict__ cursor,
                          int* __restrict__ ssrc, int E){
  int e = blockIdx.x*256 + threadIdx.x;
  if (e >= E) return;
  const int d = dst[e];
  const int p = cstart[d] + atomicAdd(&cursor[d], 1);
  ssrc[p] = src[e];
}

// ---------------- GEMM: C[n x 128] = act(A)[n x 128] @ W[128 x 128] ----------------
template<int ACT>
__global__ __launch_bounds__(256)
void k_gemm128(const float* __restrict__ A, const float* __restrict__ W,
               const float* __restrict__ bias, float* __restrict__ Cout){
  __shared__ float As[128][36];
  __shared__ float Ws[32][160];
  const int t  = threadIdx.x;
  const int r0 = blockIdx.x * 128;
  const int q  = t & 3;
  const int rp = t >> 2;

  float acc0[32], acc1[32];
  #pragma unroll
  for (int j = 0; j < 32; ++j){ acc0[j] = 0.f; acc1[j] = 0.f; }

  for (int kc = 0; kc < 128; kc += 32){
    {
      const int row = t >> 1, u = t & 1;
      const float* ap = A + (size_t)(r0+row)*CH + kc + u*16;
      float* asp = &As[row][u*16];
      #pragma unroll
      for (int i = 0; i < 4; ++i){
        float4 v = *(const float4*)(ap + 4*i);
        if (ACT){
          const float4 bb = *(const float4*)(bias + kc + u*16 + 4*i);
          v.x = fmaxf(v.x+bb.x, 0.f); v.y = fmaxf(v.y+bb.y, 0.f);
          v.z = fmaxf(v.z+bb.z, 0.f); v.w = fmaxf(v.w+bb.w, 0.f);
        }
        *(float4*)(asp + 4*i) = v;
      }
    }
    {
      const int kk = t >> 3, u = t & 7;
      const float* wp = W + (size_t)(kc+kk)*CH + u*16;
      float* wsp = &Ws[kk][(u>>1)*40 + (u&1)*16];
      #pragma unroll
      for (int i = 0; i < 4; ++i)
        *(float4*)(wsp + 4*i) = *(const float4*)(wp + 4*i);
    }
    __syncthreads();

    #pragma unroll
    for (int kk4 = 0; kk4 < 8; ++kk4){
      const float4 a0 = *(const float4*)&As[rp][kk4*4];
      const float4 a1 = *(const float4*)&As[rp+64][kk4*4];
      const float a0f[4] = {a0.x, a0.y, a0.z, a0.w};
      const float a1f[4] = {a1.x, a1.y, a1.z, a1.w};
      #pragma unroll
      for (int kk = 0; kk < 4; ++kk){
        const float av0 = a0f[kk], av1 = a1f[kk];
        #pragma unroll
        for (int j4 = 0; j4 < 8; ++j4){
          const float4 w = *(const float4*)&Ws[kk4*4+kk][q*40 + j4*4];
          acc0[j4*4+0] = fmaf(av0, w.x, acc0[j4*4+0]);
          acc0[j4*4+1] = fmaf(av0, w.y, acc0[j4*4+1]);
          acc0[j4*4+2] = fmaf(av0, w.z, acc0[j4*4+2]);
          acc0[j4*4+3] = fmaf(av0, w.w, acc0[j4*4+3]);
          acc1[j4*4+0] = fmaf(av1, w.x, acc1[j4*4+0]);
          acc1[j4*4+1] = fmaf(av1, w.y, acc1[j4*4+1]);
          acc1[j4*4+2] = fmaf(av1, w.z, acc1[j4*4+2]);
          acc1[j4*4+3] = fmaf(av1, w.w, acc1[j4*4+3]);
        }
      }
    }
    __syncthreads();
  }

  float* c0 = Cout + (size_t)(r0+rp)*CH    + q*32;
  float* c1 = Cout + (size_t)(r0+rp+64)*CH + q*32;
  #pragma unroll
  for (int j4 = 0; j4 < 8; ++j4){
    *(float4*)(c0 + j4*4) = make_float4(acc0[j4*4], acc0[j4*4+1], acc0[j4*4+2], acc0[j4*4+3]);
    *(float4*)(c1 + j4*4) = make_float4(acc1[j4*4], acc1[j4*4+1], acc1[j4*4+2], acc1[j4*4+3]);
  }
}

// ---------------- CSR aggregation ----------------
__global__ void k_agg(const float* __restrict__ hw, const float* __restrict__ dinv,
                      const int* __restrict__ start, const int* __restrict__ srcs,
                      float* __restrict__ outp){
  const int i = blockIdx.x;
  const int c = threadIdx.x;
  const float di = dinv[i];
  float acc = di * hw[(size_t)i*CH + c];
  int p = start[i];
  const int p1 = start[i+1];
  for (; p + 1 < p1; p += 2){
    const int s0 = srcs[p], s1 = srcs[p+1];
    const float w0 = dinv[s0], w1 = dinv[s1];
    acc += w0 * hw[(size_t)s0*CH + c];
    acc += w1 * hw[(size_t)s1*CH + c];
  }
  if (p < p1){
    const int s = srcs[p];
    acc += dinv[s] * hw[(size_t)s*CH + c];
  }
  outp[(size_t)i*CH + c] = di * acc;
}

// ---------------- pool -> split-bf16: p = mean_i relu(h + b2); phi+plo ≈ p ----------------
__global__ void k_pool(const float* __restrict__ h, const float* __restrict__ b2,
                       __bf16* __restrict__ phi, __bf16* __restrict__ plo){
  const int g = blockIdx.x, c = threadIdx.x;
  const float bb = b2[c];
  float acc = 0.f;
  const float* hp = h + (size_t)g*PGRAPH*CH + c;
  #pragma unroll 4
  for (int i = 0; i < PGRAPH; ++i) acc += fmaxf(hp[i*CH] + bb, 0.f);
  const float v = acc * (1.0f/64.0f);
  const __bf16 hv = (__bf16)v;
  phi[g*CH + c] = hv;
  plo[g*CH + c] = (__bf16)(v - (float)hv);
}

// ---------------- Wfc [128][65536] f32 -> transposed split-bf16 [65536][128] ----------------
__global__ __launch_bounds__(256)
void k_cvt_wfc(const float* __restrict__ Wfc, __bf16* __restrict__ wth,
               __bf16* __restrict__ wtl){
  __shared__ float ls[128][65];
  const int t  = threadIdx.x;
  const int c0 = blockIdx.x*64;

  // read 128 rows x 64 cols, coalesced 256B per row-quarter
  #pragma unroll 8
  for (int it = 0; it < 32; ++it){
    const int row = it*4 + (t>>6);
    ls[row][t&63] = Wfc[(size_t)row*FCO + c0 + (t&63)];
  }
  __syncthreads();

  // write: thread owns col (t>>2), k-quarter (t&3): 32 k values -> 4x 16B stores
  const int col = t>>2, q = t&3;
  #pragma unroll
  for (int i = 0; i < 4; ++i){
    bf16x8 h8, l8;
    #pragma unroll
    for (int j = 0; j < 8; ++j){
      const float v = ls[q*32 + i*8 + j][col];
      const __bf16 hv = (__bf16)v;
      h8[j] = hv;
      l8[j] = (__bf16)(v - (float)hv);
    }
    *(bf16x8*)(&wth[(size_t)(c0+col)*CH + q*32 + i*8]) = h8;
    *(bf16x8*)(&wtl[(size_t)(c0+col)*CH + q*32 + i*8]) = l8;
  }
}

// ---------------- FC via split-bf16 MFMA ----------------
// out[1024 x 65536] = pooled @ Wfc + bfc, 3-product split (hh + hl + lh).
// Block: 4 waves x 16 cols = 64 cols, 256 graphs (16 tiles of 16).
// Frags: A row=lane&15, k=(lane>>4)*8+j ; B col=lane&15, same k (col-major WT).
// C/D: col=lane&15, row=(lane>>4)*4+reg  [m89-verified].
__global__ __launch_bounds__(256)
void k_fc_mfma(const __bf16* __restrict__ phi, const __bf16* __restrict__ plo,
               const __bf16* __restrict__ wth, const __bf16* __restrict__ wtl,
               const float* __restrict__ bfc, float* __restrict__ out){
  const int t    = threadIdx.x;
  const int lane = t & 63, wave = t >> 6;
  const int lc   = lane & 15, kq = lane >> 4;
  const int cb   = blockIdx.x*64 + wave*16 + lc;   // this lane's output col
  const int g0   = blockIdx.y*256;

  const __bf16* bh_p = wth + (size_t)cb*CH + kq*8;
  const __bf16* bl_p = wtl + (size_t)cb*CH + kq*8;
  const __bf16* ah_p = phi + (size_t)(g0 + lc)*CH + kq*8;
  const __bf16* al_p = plo + (size_t)(g0 + lc)*CH + kq*8;

  f32x4 acc[16];
  #pragma unroll
  for (int gt = 0; gt < 16; ++gt) acc[gt] = (f32x4){0.f,0.f,0.f,0.f};

  #pragma unroll
  for (int kk = 0; kk < 4; ++kk){
    const bf16x8 bh = *(const bf16x8*)(bh_p + kk*32);
    const bf16x8 bl = *(const bf16x8*)(bl_p + kk*32);
    #pragma unroll
    for (int gt = 0; gt < 16; ++gt){
      const bf16x8 ah = *(const bf16x8*)(ah_p + (size_t)gt*16*CH + kk*32);
      const bf16x8 al = *(const bf16x8*)(al_p + (size_t)gt*16*CH + kk*32);
      acc[gt] = __builtin_amdgcn_mfma_f32_16x16x32_bf16(ah, bh, acc[gt], 0, 0, 0);
      acc[gt] = __builtin_amdgcn_mfma_f32_16x16x32_bf16(ah, bl, acc[gt], 0, 0, 0);
      acc[gt] = __builtin_amdgcn_mfma_f32_16x16x32_bf16(al, bh, acc[gt], 0, 0, 0);
    }
  }

  const float bias = bfc[cb];
  #pragma unroll
  for (int gt = 0; gt < 16; ++gt){
    const int gr = g0 + gt*16 + kq*4;
    #pragma unroll
    for (int r = 0; r < 4; ++r)
      out[(size_t)(gr + r)*FCO + cb] = acc[gt][r] + bias;
  }
}

// ---------------- launch ----------------

extern "C" void kernel_launch(void* const* d_in, const int* in_sizes, int n_in,
                              void* d_out, int out_size, void* d_ws, size_t ws_size,
                              hipStream_t stream){
  const float* x   = (const float*)d_in[0];
  const int*   ei  = (const int*)d_in[1];   // [2, E] int32 (jax x64 off)
  const float* W1  = (const float*)d_in[3];
  const float* b1  = (const float*)d_in[4];
  const float* W2  = (const float*)d_in[5];
  const float* b2  = (const float*)d_in[6];
  const float* Wfc = (const float*)d_in[7];
  const float* bfc = (const float*)d_in[8];
  float* out = (float*)d_out;
  const int E = in_sizes[1] / 2;

  // workspace layout (~75 MB)
  float* bufA   = (float*)d_ws;                      // 33.5 MB (also reused for WT hi/lo)
  float* bufB   = bufA + (size_t)NODES*CH;           // 33.5 MB
  float* dinv   = bufB + (size_t)NODES*CH;           // 256 KB
  int*   deg    = (int*)(dinv + NODES);              // 256 KB
  int*   cstart = deg + NODES;                       // NODES+1 (+256 reserve)
  int*   cursor = cstart + NODES + 256;              // 256 KB
  int*   bsums  = cursor + NODES;                    // 1 KB
  int*   ssrc   = bsums + 256;                       // 4 MB
  __bf16* phi   = (__bf16*)(ssrc + E);               // 256 KB
  __bf16* plo   = phi + (size_t)NGRAPH*CH;           // 256 KB

  // WT hi/lo carved from bufA (dead after agg2): 2 x 16.78 MB = 33.55 MB exactly
  __bf16* wth = (__bf16*)bufA;
  __bf16* wtl = wth + (size_t)FCO*CH;

  const int* esrc = ei;
  const int* edst = ei + E;

  hipMemsetAsync(deg,    0, NODES*sizeof(int), stream);
  hipMemsetAsync(cursor, 0, NODES*sizeof(int), stream);

  k_degree <<<(E+255)/256, 256, 0, stream>>>(edst, deg, E);
  k_dinv   <<<NODES/256,   256, 0, stream>>>(deg, dinv);
  k_scan1  <<<NODES/256,   256, 0, stream>>>(deg, cstart, bsums);
  k_scan2  <<<1,           256, 0, stream>>>(bsums);
  k_scan3  <<<NODES/256,   256, 0, stream>>>(cstart, bsums, E);
  k_scatter<<<(E+255)/256, 256, 0, stream>>>(esrc, edst, cstart, cursor, ssrc, E);

  k_gemm128<0><<<NODES/128, 256, 0, stream>>>(x,    W1, nullptr, bufA);   // bufA = x@W1
  k_agg       <<<NODES, CH, 0, stream>>>(bufA, dinv, cstart, ssrc, bufB); // bufB = agg1
  k_gemm128<1><<<NODES/128, 256, 0, stream>>>(bufB, W2, b1,     bufA);    // bufA = relu(agg1+b1)@W2
  k_agg       <<<NODES, CH, 0, stream>>>(bufA, dinv, cstart, ssrc, bufB); // bufB = agg2

  // bufA now dead -> reuse for transposed split-bf16 Wfc
  k_cvt_wfc <<<FCO/64, 256, 0, stream>>>(Wfc, wth, wtl);
  k_pool    <<<NGRAPH, CH, 0, stream>>>(bufB, b2, phi, plo);
  k_fc_mfma <<<dim3(FCO/64, NGRAPH/256), 256, 0, stream>>>(phi, plo, wth, wtl, bfc, out);
}

// Round 7
// 530.121 us; speedup vs baseline: 1.2580x; 1.2580x over previous
//
#include <hip/hip_runtime.h>
#include <hip/hip_bf16.h>
#include <cstdint>

#define NODES  65536
#define CH     128
#define NGRAPH 1024
#define PGRAPH 64
#define FCO    65536

typedef __bf16 bf16x8 __attribute__((ext_vector_type(8)));
typedef float  f32x4  __attribute__((ext_vector_type(4)));

// ---------------- graph preprocessing ----------------

__global__ void k_degree(const int* __restrict__ dst, int* __restrict__ deg, int E){
  int e = blockIdx.x*256 + threadIdx.x;
  if (e < E) atomicAdd(&deg[dst[e]], 1);
}

__global__ void k_dinv(const int* __restrict__ deg, float* __restrict__ dinv){
  int i = blockIdx.x*256 + threadIdx.x;
  dinv[i] = 1.0f / sqrtf((float)(deg[i] + 1));   // self-loop -> deg+1 >= 1
}

__global__ void k_scan1(const int* __restrict__ deg, int* __restrict__ excl,
                        int* __restrict__ bsums){
  __shared__ int tmp[256];
  const int t = threadIdx.x;
  const int gid = blockIdx.x*256 + t;
  const int v = deg[gid];
  tmp[t] = v;
  __syncthreads();
  #pragma unroll
  for (int off = 1; off < 256; off <<= 1){
    int x = (t >= off) ? tmp[t-off] : 0;
    __syncthreads();
    tmp[t] += x;
    __syncthreads();
  }
  excl[gid] = tmp[t] - v;
  if (t == 255) bsums[blockIdx.x] = tmp[255];
}

__global__ void k_scan2(int* __restrict__ bsums){
  __shared__ int tmp[256];
  const int t = threadIdx.x;
  const int v = bsums[t];
  tmp[t] = v;
  __syncthreads();
  #pragma unroll
  for (int off = 1; off < 256; off <<= 1){
    int x = (t >= off) ? tmp[t-off] : 0;
    __syncthreads();
    tmp[t] += x;
    __syncthreads();
  }
  bsums[t] = tmp[t] - v;   // exclusive
}

__global__ void k_scan3(int* __restrict__ cstart, const int* __restrict__ bsums, int E){
  const int gid = blockIdx.x*256 + threadIdx.x;
  cstart[gid] += bsums[blockIdx.x];
  if (gid == 0) cstart[NODES] = E;
}

__global__ void k_scatter(const int* __restrict__ src, const int* __restrict__ dst,
                          const int* __restrict__ cstart, int* __restrict__ cursor,
                          int* __restrict__ ssrc, int E){
  int e = blockIdx.x*256 + threadIdx.x;
  if (e >= E) return;
  const int d = dst[e];
  const int p = cstart[d] + atomicAdd(&cursor[d], 1);
  ssrc[p] = src[e];
}

// ---------------- GEMM: C[n x 128] = act(A)[n x 128] @ W[128 x 128] ----------------
template<int ACT>
__global__ __launch_bounds__(256)
void k_gemm128(const float* __restrict__ A, const float* __restrict__ W,
               const float* __restrict__ bias, float* __restrict__ Cout){
  __shared__ float As[128][36];
  __shared__ float Ws[32][160];
  const int t  = threadIdx.x;
  const int r0 = blockIdx.x * 128;
  const int q  = t & 3;
  const int rp = t >> 2;

  float acc0[32], acc1[32];
  #pragma unroll
  for (int j = 0; j < 32; ++j){ acc0[j] = 0.f; acc1[j] = 0.f; }

  for (int kc = 0; kc < 128; kc += 32){
    {
      const int row = t >> 1, u = t & 1;
      const float* ap = A + (size_t)(r0+row)*CH + kc + u*16;
      float* asp = &As[row][u*16];
      #pragma unroll
      for (int i = 0; i < 4; ++i){
        float4 v = *(const float4*)(ap + 4*i);
        if (ACT){
          const float4 bb = *(const float4*)(bias + kc + u*16 + 4*i);
          v.x = fmaxf(v.x+bb.x, 0.f); v.y = fmaxf(v.y+bb.y, 0.f);
          v.z = fmaxf(v.z+bb.z, 0.f); v.w = fmaxf(v.w+bb.w, 0.f);
        }
        *(float4*)(asp + 4*i) = v;
      }
    }
    {
      const int kk = t >> 3, u = t & 7;
      const float* wp = W + (size_t)(kc+kk)*CH + u*16;
      float* wsp = &Ws[kk][(u>>1)*40 + (u&1)*16];
      #pragma unroll
      for (int i = 0; i < 4; ++i)
        *(float4*)(wsp + 4*i) = *(const float4*)(wp + 4*i);
    }
    __syncthreads();

    #pragma unroll
    for (int kk4 = 0; kk4 < 8; ++kk4){
      const float4 a0 = *(const float4*)&As[rp][kk4*4];
      const float4 a1 = *(const float4*)&As[rp+64][kk4*4];
      const float a0f[4] = {a0.x, a0.y, a0.z, a0.w};
      const float a1f[4] = {a1.x, a1.y, a1.z, a1.w};
      #pragma unroll
      for (int kk = 0; kk < 4; ++kk){
        const float av0 = a0f[kk], av1 = a1f[kk];
        #pragma unroll
        for (int j4 = 0; j4 < 8; ++j4){
          const float4 w = *(const float4*)&Ws[kk4*4+kk][q*40 + j4*4];
          acc0[j4*4+0] = fmaf(av0, w.x, acc0[j4*4+0]);
          acc0[j4*4+1] = fmaf(av0, w.y, acc0[j4*4+1]);
          acc0[j4*4+2] = fmaf(av0, w.z, acc0[j4*4+2]);
          acc0[j4*4+3] = fmaf(av0, w.w, acc0[j4*4+3]);
          acc1[j4*4+0] = fmaf(av1, w.x, acc1[j4*4+0]);
          acc1[j4*4+1] = fmaf(av1, w.y, acc1[j4*4+1]);
          acc1[j4*4+2] = fmaf(av1, w.z, acc1[j4*4+2]);
          acc1[j4*4+3] = fmaf(av1, w.w, acc1[j4*4+3]);
        }
      }
    }
    __syncthreads();
  }

  float* c0 = Cout + (size_t)(r0+rp)*CH    + q*32;
  float* c1 = Cout + (size_t)(r0+rp+64)*CH + q*32;
  #pragma unroll
  for (int j4 = 0; j4 < 8; ++j4){
    *(float4*)(c0 + j4*4) = make_float4(acc0[j4*4], acc0[j4*4+1], acc0[j4*4+2], acc0[j4*4+3]);
    *(float4*)(c1 + j4*4) = make_float4(acc1[j4*4], acc1[j4*4+1], acc1[j4*4+2], acc1[j4*4+3]);
  }
}

// ---------------- CSR aggregation ----------------
__global__ void k_agg(const float* __restrict__ hw, const float* __restrict__ dinv,
                      const int* __restrict__ start, const int* __restrict__ srcs,
                      float* __restrict__ outp){
  const int i = blockIdx.x;
  const int c = threadIdx.x;
  const float di = dinv[i];
  float acc = di * hw[(size_t)i*CH + c];
  int p = start[i];
  const int p1 = start[i+1];
  for (; p + 1 < p1; p += 2){
    const int s0 = srcs[p], s1 = srcs[p+1];
    const float w0 = dinv[s0], w1 = dinv[s1];
    acc += w0 * hw[(size_t)s0*CH + c];
    acc += w1 * hw[(size_t)s1*CH + c];
  }
  if (p < p1){
    const int s = srcs[p];
    acc += dinv[s] * hw[(size_t)s*CH + c];
  }
  outp[(size_t)i*CH + c] = di * acc;
}

// ---------------- pool -> split-bf16: p = mean_i relu(h + b2); phi+plo ≈ p ----------------
__global__ void k_pool(const float* __restrict__ h, const float* __restrict__ b2,
                       __bf16* __restrict__ phi, __bf16* __restrict__ plo){
  const int g = blockIdx.x, c = threadIdx.x;
  const float bb = b2[c];
  float acc = 0.f;
  const float* hp = h + (size_t)g*PGRAPH*CH + c;
  #pragma unroll 4
  for (int i = 0; i < PGRAPH; ++i) acc += fmaxf(hp[i*CH] + bb, 0.f);
  const float v = acc * (1.0f/64.0f);
  const __bf16 hv = (__bf16)v;
  phi[g*CH + c] = hv;
  plo[g*CH + c] = (__bf16)(v - (float)hv);
}

// ---------------- Wfc [128][65536] f32 -> transposed split-bf16 [65536][128] ----------------
__global__ __launch_bounds__(256)
void k_cvt_wfc(const float* __restrict__ Wfc, __bf16* __restrict__ wth,
               __bf16* __restrict__ wtl){
  __shared__ float ls[128][65];
  const int t  = threadIdx.x;
  const int c0 = blockIdx.x*64;

  #pragma unroll 8
  for (int it = 0; it < 32; ++it){
    const int row = it*4 + (t>>6);
    ls[row][t&63] = Wfc[(size_t)row*FCO + c0 + (t&63)];
  }
  __syncthreads();

  const int col = t>>2, q = t&3;
  #pragma unroll
  for (int i = 0; i < 4; ++i){
    bf16x8 h8, l8;
    #pragma unroll
    for (int j = 0; j < 8; ++j){
      const float v = ls[q*32 + i*8 + j][col];
      const __bf16 hv = (__bf16)v;
      h8[j] = hv;
      l8[j] = (__bf16)(v - (float)hv);
    }
    *(bf16x8*)(&wth[(size_t)(c0+col)*CH + q*32 + i*8]) = h8;
    *(bf16x8*)(&wtl[(size_t)(c0+col)*CH + q*32 + i*8]) = l8;
  }
}

// ---------------- FC via split-bf16 MFMA, A-resident ----------------
// Block: 64 graphs x 2048 cols. 4 waves; wave owns contiguous 512 cols.
// A-frags (pooled hi/lo, 64 graphs x 128 k) in registers ONCE (128 VGPR);
// 32 col-iterations stream W with ping-pong prefetch; 48 MFMA per iter.
// Frag maps (validated in R6): A row=lane&15, k=(lane>>4)*8+j; B col=lane&15;
// C/D col=lane&15, row=(lane>>4)*4+reg.

#define LOADB(BH, BL, ITC) do{ \
  const size_t cb_ = (size_t)(c0w + (ITC)*16 + lc)*CH + kq*8; \
  BH[0] = *(const bf16x8*)(wth + cb_);      BL[0] = *(const bf16x8*)(wtl + cb_); \
  BH[1] = *(const bf16x8*)(wth + cb_ + 32); BL[1] = *(const bf16x8*)(wtl + cb_ + 32); \
  BH[2] = *(const bf16x8*)(wth + cb_ + 64); BL[2] = *(const bf16x8*)(wtl + cb_ + 64); \
  BH[3] = *(const bf16x8*)(wth + cb_ + 96); BL[3] = *(const bf16x8*)(wtl + cb_ + 96); \
}while(0)

#define DOCOL(BH, BL, ITC) do{ \
  f32x4 q0 = {0.f,0.f,0.f,0.f}, q1 = {0.f,0.f,0.f,0.f}; \
  f32x4 q2 = {0.f,0.f,0.f,0.f}, q3 = {0.f,0.f,0.f,0.f}; \
  _Pragma("unroll") \
  for (int kk = 0; kk < 4; ++kk){ \
    q0 = __builtin_amdgcn_mfma_f32_16x16x32_bf16(ah[0][kk], BH[kk], q0, 0,0,0); \
    q1 = __builtin_amdgcn_mfma_f32_16x16x32_bf16(ah[1][kk], BH[kk], q1, 0,0,0); \
    q2 = __builtin_amdgcn_mfma_f32_16x16x32_bf16(ah[2][kk], BH[kk], q2, 0,0,0); \
    q3 = __builtin_amdgcn_mfma_f32_16x16x32_bf16(ah[3][kk], BH[kk], q3, 0,0,0); \
    q0 = __builtin_amdgcn_mfma_f32_16x16x32_bf16(ah[0][kk], BL[kk], q0, 0,0,0); \
    q1 = __builtin_amdgcn_mfma_f32_16x16x32_bf16(ah[1][kk], BL[kk], q1, 0,0,0); \
    q2 = __builtin_amdgcn_mfma_f32_16x16x32_bf16(ah[2][kk], BL[kk], q2, 0,0,0); \
    q3 = __builtin_amdgcn_mfma_f32_16x16x32_bf16(ah[3][kk], BL[kk], q3, 0,0,0); \
    q0 = __builtin_amdgcn_mfma_f32_16x16x32_bf16(al[0][kk], BH[kk], q0, 0,0,0); \
    q1 = __builtin_amdgcn_mfma_f32_16x16x32_bf16(al[1][kk], BH[kk], q1, 0,0,0); \
    q2 = __builtin_amdgcn_mfma_f32_16x16x32_bf16(al[2][kk], BH[kk], q2, 0,0,0); \
    q3 = __builtin_amdgcn_mfma_f32_16x16x32_bf16(al[3][kk], BH[kk], q3, 0,0,0); \
  } \
  const int cc = c0w + (ITC)*16 + lc; \
  const float bias = bfc[cc]; \
  float* op = out + cc + (size_t)(g0 + kq*4)*FCO; \
  _Pragma("unroll") \
  for (int r = 0; r < 4; ++r){ \
    op[(size_t)(r     )*FCO] = q0[r] + bias; \
    op[(size_t)(r + 16)*FCO] = q1[r] + bias; \
    op[(size_t)(r + 32)*FCO] = q2[r] + bias; \
    op[(size_t)(r + 48)*FCO] = q3[r] + bias; \
  } \
}while(0)

__global__ __launch_bounds__(256)
void k_fc_mfma(const __bf16* __restrict__ phi, const __bf16* __restrict__ plo,
               const __bf16* __restrict__ wth, const __bf16* __restrict__ wtl,
               const float* __restrict__ bfc, float* __restrict__ out){
  const int t    = threadIdx.x;
  const int lane = t & 63, wave = t >> 6;
  const int lc   = lane & 15, kq = lane >> 4;
  const int g0   = blockIdx.y*64;
  const int c0w  = blockIdx.x*2048 + wave*512;   // wave's contiguous col range

  // A fragments resident: 4 graph-tiles x 4 k-chunks, hi+lo
  bf16x8 ah[4][4], al[4][4];
  #pragma unroll
  for (int gt = 0; gt < 4; ++gt){
    const __bf16* pa = phi + (size_t)(g0 + gt*16 + lc)*CH + kq*8;
    const __bf16* pb = plo + (size_t)(g0 + gt*16 + lc)*CH + kq*8;
    #pragma unroll
    for (int kk = 0; kk < 4; ++kk){
      ah[gt][kk] = *(const bf16x8*)(pa + kk*32);
      al[gt][kk] = *(const bf16x8*)(pb + kk*32);
    }
  }

  bf16x8 bhA[4], blA[4], bhB[4], blB[4];
  LOADB(bhA, blA, 0);
  #pragma unroll 1
  for (int it = 0; it < 32; it += 2){
    LOADB(bhB, blB, it+1);
    DOCOL(bhA, blA, it);
    if (it + 2 < 32) LOADB(bhA, blA, it+2);
    DOCOL(bhB, blB, it+1);
  }
}

// ---------------- launch ----------------

extern "C" void kernel_launch(void* const* d_in, const int* in_sizes, int n_in,
                              void* d_out, int out_size, void* d_ws, size_t ws_size,
                              hipStream_t stream){
  const float* x   = (const float*)d_in[0];
  const int*   ei  = (const int*)d_in[1];   // [2, E] int32 (jax x64 off)
  const float* W1  = (const float*)d_in[3];
  const float* b1  = (const float*)d_in[4];
  const float* W2  = (const float*)d_in[5];
  const float* b2  = (const float*)d_in[6];
  const float* Wfc = (const float*)d_in[7];
  const float* bfc = (const float*)d_in[8];
  float* out = (float*)d_out;
  const int E = in_sizes[1] / 2;

  // workspace layout (~75 MB)
  float* bufA   = (float*)d_ws;                      // 33.5 MB (reused for WT hi/lo)
  float* bufB   = bufA + (size_t)NODES*CH;           // 33.5 MB
  float* dinv   = bufB + (size_t)NODES*CH;           // 256 KB
  int*   deg    = (int*)(dinv + NODES);              // 256 KB
  int*   cstart = deg + NODES;                       // NODES+1 (+256 reserve)
  int*   cursor = cstart + NODES + 256;              // 256 KB
  int*   bsums  = cursor + NODES;                    // 1 KB
  int*   ssrc   = bsums + 256;                       // 4 MB
  __bf16* phi   = (__bf16*)(ssrc + E);               // 256 KB
  __bf16* plo   = phi + (size_t)NGRAPH*CH;           // 256 KB

  __bf16* wth = (__bf16*)bufA;                       // 16.78 MB
  __bf16* wtl = wth + (size_t)FCO*CH;                // 16.78 MB

  const int* esrc = ei;
  const int* edst = ei + E;

  hipMemsetAsync(deg,    0, NODES*sizeof(int), stream);
  hipMemsetAsync(cursor, 0, NODES*sizeof(int), stream);

  k_degree <<<(E+255)/256, 256, 0, stream>>>(edst, deg, E);
  k_dinv   <<<NODES/256,   256, 0, stream>>>(deg, dinv);
  k_scan1  <<<NODES/256,   256, 0, stream>>>(deg, cstart, bsums);
  k_scan2  <<<1,           256, 0, stream>>>(bsums);
  k_scan3  <<<NODES/256,   256, 0, stream>>>(cstart, bsums, E);
  k_scatter<<<(E+255)/256, 256, 0, stream>>>(esrc, edst, cstart, cursor, ssrc, E);

  k_gemm128<0><<<NODES/128, 256, 0, stream>>>(x,    W1, nullptr, bufA);   // bufA = x@W1
  k_agg       <<<NODES, CH, 0, stream>>>(bufA, dinv, cstart, ssrc, bufB); // bufB = agg1
  k_gemm128<1><<<NODES/128, 256, 0, stream>>>(bufB, W2, b1,     bufA);    // bufA = relu(agg1+b1)@W2
  k_agg       <<<NODES, CH, 0, stream>>>(bufA, dinv, cstart, ssrc, bufB); // bufB = agg2

  // bufA dead -> transposed split-bf16 Wfc
  k_cvt_wfc <<<FCO/64, 256, 0, stream>>>(Wfc, wth, wtl);
  k_pool    <<<NGRAPH, CH, 0, stream>>>(bufB, b2, phi, plo);
  k_fc_mfma <<<dim3(32, NGRAPH/64), 256, 0, stream>>>(phi, plo, wth, wtl, bfc, out);
}

// Round 8
// 519.337 us; speedup vs baseline: 1.2841x; 1.0208x over previous
//
#include <hip/hip_runtime.h>
#include <hip/hip_bf16.h>
#include <cstdint>

#define NODES  65536
#define CH     128
#define NGRAPH 1024
#define PGRAPH 64
#define FCO    65536

typedef __bf16 bf16x8 __attribute__((ext_vector_type(8)));
typedef float  f32x4  __attribute__((ext_vector_type(4)));

// ---------------- graph preprocessing ----------------

// zero deg + cursor (replaces 2x hipMemsetAsync: rocclr fill blit cost ~160us each in graph)
__global__ void k_zero2(int* __restrict__ a, int* __restrict__ b){
  const int i = blockIdx.x*256 + threadIdx.x;
  ((int4*)a)[i] = make_int4(0,0,0,0);
  ((int4*)b)[i] = make_int4(0,0,0,0);
}

__global__ void k_degree(const int* __restrict__ dst, int* __restrict__ deg, int E){
  int e = blockIdx.x*256 + threadIdx.x;
  if (e < E) atomicAdd(&deg[dst[e]], 1);
}

__global__ void k_dinv(const int* __restrict__ deg, float* __restrict__ dinv){
  int i = blockIdx.x*256 + threadIdx.x;
  dinv[i] = 1.0f / sqrtf((float)(deg[i] + 1));   // self-loop -> deg+1 >= 1
}

__global__ void k_scan1(const int* __restrict__ deg, int* __restrict__ excl,
                        int* __restrict__ bsums){
  __shared__ int tmp[256];
  const int t = threadIdx.x;
  const int gid = blockIdx.x*256 + t;
  const int v = deg[gid];
  tmp[t] = v;
  __syncthreads();
  #pragma unroll
  for (int off = 1; off < 256; off <<= 1){
    int x = (t >= off) ? tmp[t-off] : 0;
    __syncthreads();
    tmp[t] += x;
    __syncthreads();
  }
  excl[gid] = tmp[t] - v;
  if (t == 255) bsums[blockIdx.x] = tmp[255];
}

__global__ void k_scan2(int* __restrict__ bsums){
  __shared__ int tmp[256];
  const int t = threadIdx.x;
  const int v = bsums[t];
  tmp[t] = v;
  __syncthreads();
  #pragma unroll
  for (int off = 1; off < 256; off <<= 1){
    int x = (t >= off) ? tmp[t-off] : 0;
    __syncthreads();
    tmp[t] += x;
    __syncthreads();
  }
  bsums[t] = tmp[t] - v;   // exclusive
}

__global__ void k_scan3(int* __restrict__ cstart, const int* __restrict__ bsums, int E){
  const int gid = blockIdx.x*256 + threadIdx.x;
  cstart[gid] += bsums[blockIdx.x];
  if (gid == 0) cstart[NODES] = E;
}

__global__ void k_scatter(const int* __restrict__ src, const int* __restrict__ dst,
                          const int* __restrict__ cstart, int* __restrict__ cursor,
                          int* __restrict__ ssrc, int E){
  int e = blockIdx.x*256 + threadIdx.x;
  if (e >= E) return;
  const int d = dst[e];
  const int p = cstart[d] + atomicAdd(&cursor[d], 1);
  ssrc[p] = src[e];
}

// ---------------- GEMM: C[n x 128] = act(A)[n x 128] @ W[128 x 128] ----------------
template<int ACT>
__global__ __launch_bounds__(256)
void k_gemm128(const float* __restrict__ A, const float* __restrict__ W,
               const float* __restrict__ bias, float* __restrict__ Cout){
  __shared__ float As[128][36];
  __shared__ float Ws[32][160];
  const int t  = threadIdx.x;
  const int r0 = blockIdx.x * 128;
  const int q  = t & 3;
  const int rp = t >> 2;

  float acc0[32], acc1[32];
  #pragma unroll
  for (int j = 0; j < 32; ++j){ acc0[j] = 0.f; acc1[j] = 0.f; }

  for (int kc = 0; kc < 128; kc += 32){
    {
      const int row = t >> 1, u = t & 1;
      const float* ap = A + (size_t)(r0+row)*CH + kc + u*16;
      float* asp = &As[row][u*16];
      #pragma unroll
      for (int i = 0; i < 4; ++i){
        float4 v = *(const float4*)(ap + 4*i);
        if (ACT){
          const float4 bb = *(const float4*)(bias + kc + u*16 + 4*i);
          v.x = fmaxf(v.x+bb.x, 0.f); v.y = fmaxf(v.y+bb.y, 0.f);
          v.z = fmaxf(v.z+bb.z, 0.f); v.w = fmaxf(v.w+bb.w, 0.f);
        }
        *(float4*)(asp + 4*i) = v;
      }
    }
    {
      const int kk = t >> 3, u = t & 7;
      const float* wp = W + (size_t)(kc+kk)*CH + u*16;
      float* wsp = &Ws[kk][(u>>1)*40 + (u&1)*16];
      #pragma unroll
      for (int i = 0; i < 4; ++i)
        *(float4*)(wsp + 4*i) = *(const float4*)(wp + 4*i);
    }
    __syncthreads();

    #pragma unroll
    for (int kk4 = 0; kk4 < 8; ++kk4){
      const float4 a0 = *(const float4*)&As[rp][kk4*4];
      const float4 a1 = *(const float4*)&As[rp+64][kk4*4];
      const float a0f[4] = {a0.x, a0.y, a0.z, a0.w};
      const float a1f[4] = {a1.x, a1.y, a1.z, a1.w};
      #pragma unroll
      for (int kk = 0; kk < 4; ++kk){
        const float av0 = a0f[kk], av1 = a1f[kk];
        #pragma unroll
        for (int j4 = 0; j4 < 8; ++j4){
          const float4 w = *(const float4*)&Ws[kk4*4+kk][q*40 + j4*4];
          acc0[j4*4+0] = fmaf(av0, w.x, acc0[j4*4+0]);
          acc0[j4*4+1] = fmaf(av0, w.y, acc0[j4*4+1]);
          acc0[j4*4+2] = fmaf(av0, w.z, acc0[j4*4+2]);
          acc0[j4*4+3] = fmaf(av0, w.w, acc0[j4*4+3]);
          acc1[j4*4+0] = fmaf(av1, w.x, acc1[j4*4+0]);
          acc1[j4*4+1] = fmaf(av1, w.y, acc1[j4*4+1]);
          acc1[j4*4+2] = fmaf(av1, w.z, acc1[j4*4+2]);
          acc1[j4*4+3] = fmaf(av1, w.w, acc1[j4*4+3]);
        }
      }
    }
    __syncthreads();
  }

  float* c0 = Cout + (size_t)(r0+rp)*CH    + q*32;
  float* c1 = Cout + (size_t)(r0+rp+64)*CH + q*32;
  #pragma unroll
  for (int j4 = 0; j4 < 8; ++j4){
    *(float4*)(c0 + j4*4) = make_float4(acc0[j4*4], acc0[j4*4+1], acc0[j4*4+2], acc0[j4*4+3]);
    *(float4*)(c1 + j4*4) = make_float4(acc1[j4*4], acc1[j4*4+1], acc1[j4*4+2], acc1[j4*4+3]);
  }
}

// ---------------- CSR aggregation ----------------
__global__ void k_agg(const float* __restrict__ hw, const float* __restrict__ dinv,
                      const int* __restrict__ start, const int* __restrict__ srcs,
                      float* __restrict__ outp){
  const int i = blockIdx.x;
  const int c = threadIdx.x;
  const float di = dinv[i];
  float acc = di * hw[(size_t)i*CH + c];
  int p = start[i];
  const int p1 = start[i+1];
  for (; p + 1 < p1; p += 2){
    const int s0 = srcs[p], s1 = srcs[p+1];
    const float w0 = dinv[s0], w1 = dinv[s1];
    acc += w0 * hw[(size_t)s0*CH + c];
    acc += w1 * hw[(size_t)s1*CH + c];
  }
  if (p < p1){
    const int s = srcs[p];
    acc += dinv[s] * hw[(size_t)s*CH + c];
  }
  outp[(size_t)i*CH + c] = di * acc;
}

// ---------------- pool -> split-bf16: p = mean_i relu(h + b2); phi+plo ≈ p ----------------
__global__ void k_pool(const float* __restrict__ h, const float* __restrict__ b2,
                       __bf16* __restrict__ phi, __bf16* __restrict__ plo){
  const int g = blockIdx.x, c = threadIdx.x;
  const float bb = b2[c];
  float acc = 0.f;
  const float* hp = h + (size_t)g*PGRAPH*CH + c;
  #pragma unroll 4
  for (int i = 0; i < PGRAPH; ++i) acc += fmaxf(hp[i*CH] + bb, 0.f);
  const float v = acc * (1.0f/64.0f);
  const __bf16 hv = (__bf16)v;
  phi[g*CH + c] = hv;
  plo[g*CH + c] = (__bf16)(v - (float)hv);
}

// ---------------- Wfc [128][65536] f32 -> transposed split-bf16 [65536][128] ----------------
__global__ __launch_bounds__(256)
void k_cvt_wfc(const float* __restrict__ Wfc, __bf16* __restrict__ wth,
               __bf16* __restrict__ wtl){
  __shared__ float ls[128][65];
  const int t  = threadIdx.x;
  const int c0 = blockIdx.x*64;

  #pragma unroll 8
  for (int it = 0; it < 32; ++it){
    const int row = it*4 + (t>>6);
    ls[row][t&63] = Wfc[(size_t)row*FCO + c0 + (t&63)];
  }
  __syncthreads();

  const int col = t>>2, q = t&3;
  #pragma unroll
  for (int i = 0; i < 4; ++i){
    bf16x8 h8, l8;
    #pragma unroll
    for (int j = 0; j < 8; ++j){
      const float v = ls[q*32 + i*8 + j][col];
      const __bf16 hv = (__bf16)v;
      h8[j] = hv;
      l8[j] = (__bf16)(v - (float)hv);
    }
    *(bf16x8*)(&wth[(size_t)(c0+col)*CH + q*32 + i*8]) = h8;
    *(bf16x8*)(&wtl[(size_t)(c0+col)*CH + q*32 + i*8]) = l8;
  }
}

// ---------------- FC via split-bf16 MFMA, A-resident ----------------
// Block: 64 graphs x 2048 cols. 4 waves; wave owns contiguous 512 cols.
// A-frags in registers once; 32 col-iterations stream W, ping-pong prefetch.

#define LOADB(BH, BL, ITC) do{ \
  const size_t cb_ = (size_t)(c0w + (ITC)*16 + lc)*CH + kq*8; \
  BH[0] = *(const bf16x8*)(wth + cb_);      BL[0] = *(const bf16x8*)(wtl + cb_); \
  BH[1] = *(const bf16x8*)(wth + cb_ + 32); BL[1] = *(const bf16x8*)(wtl + cb_ + 32); \
  BH[2] = *(const bf16x8*)(wth + cb_ + 64); BL[2] = *(const bf16x8*)(wtl + cb_ + 64); \
  BH[3] = *(const bf16x8*)(wth + cb_ + 96); BL[3] = *(const bf16x8*)(wtl + cb_ + 96); \
}while(0)

#define DOCOL(BH, BL, ITC) do{ \
  f32x4 q0 = {0.f,0.f,0.f,0.f}, q1 = {0.f,0.f,0.f,0.f}; \
  f32x4 q2 = {0.f,0.f,0.f,0.f}, q3 = {0.f,0.f,0.f,0.f}; \
  _Pragma("unroll") \
  for (int kk = 0; kk < 4; ++kk){ \
    q0 = __builtin_amdgcn_mfma_f32_16x16x32_bf16(ah[0][kk], BH[kk], q0, 0,0,0); \
    q1 = __builtin_amdgcn_mfma_f32_16x16x32_bf16(ah[1][kk], BH[kk], q1, 0,0,0); \
    q2 = __builtin_amdgcn_mfma_f32_16x16x32_bf16(ah[2][kk], BH[kk], q2, 0,0,0); \
    q3 = __builtin_amdgcn_mfma_f32_16x16x32_bf16(ah[3][kk], BH[kk], q3, 0,0,0); \
    q0 = __builtin_amdgcn_mfma_f32_16x16x32_bf16(ah[0][kk], BL[kk], q0, 0,0,0); \
    q1 = __builtin_amdgcn_mfma_f32_16x16x32_bf16(ah[1][kk], BL[kk], q1, 0,0,0); \
    q2 = __builtin_amdgcn_mfma_f32_16x16x32_bf16(ah[2][kk], BL[kk], q2, 0,0,0); \
    q3 = __builtin_amdgcn_mfma_f32_16x16x32_bf16(ah[3][kk], BL[kk], q3, 0,0,0); \
    q0 = __builtin_amdgcn_mfma_f32_16x16x32_bf16(al[0][kk], BH[kk], q0, 0,0,0); \
    q1 = __builtin_amdgcn_mfma_f32_16x16x32_bf16(al[1][kk], BH[kk], q1, 0,0,0); \
    q2 = __builtin_amdgcn_mfma_f32_16x16x32_bf16(al[2][kk], BH[kk], q2, 0,0,0); \
    q3 = __builtin_amdgcn_mfma_f32_16x16x32_bf16(al[3][kk], BH[kk], q3, 0,0,0); \
  } \
  const int cc = c0w + (ITC)*16 + lc; \
  const float bias = bfc[cc]; \
  float* op = out + cc + (size_t)(g0 + kq*4)*FCO; \
  _Pragma("unroll") \
  for (int r = 0; r < 4; ++r){ \
    op[(size_t)(r     )*FCO] = q0[r] + bias; \
    op[(size_t)(r + 16)*FCO] = q1[r] + bias; \
    op[(size_t)(r + 32)*FCO] = q2[r] + bias; \
    op[(size_t)(r + 48)*FCO] = q3[r] + bias; \
  } \
}while(0)

__global__ __launch_bounds__(256)
void k_fc_mfma(const __bf16* __restrict__ phi, const __bf16* __restrict__ plo,
               const __bf16* __restrict__ wth, const __bf16* __restrict__ wtl,
               const float* __restrict__ bfc, float* __restrict__ out){
  const int t    = threadIdx.x;
  const int lane = t & 63, wave = t >> 6;
  const int lc   = lane & 15, kq = lane >> 4;
  const int g0   = blockIdx.y*64;
  const int c0w  = blockIdx.x*2048 + wave*512;   // wave's contiguous col range

  bf16x8 ah[4][4], al[4][4];
  #pragma unroll
  for (int gt = 0; gt < 4; ++gt){
    const __bf16* pa = phi + (size_t)(g0 + gt*16 + lc)*CH + kq*8;
    const __bf16* pb = plo + (size_t)(g0 + gt*16 + lc)*CH + kq*8;
    #pragma unroll
    for (int kk = 0; kk < 4; ++kk){
      ah[gt][kk] = *(const bf16x8*)(pa + kk*32);
      al[gt][kk] = *(const bf16x8*)(pb + kk*32);
    }
  }

  bf16x8 bhA[4], blA[4], bhB[4], blB[4];
  LOADB(bhA, blA, 0);
  #pragma unroll 1
  for (int it = 0; it < 32; it += 2){
    LOADB(bhB, blB, it+1);
    DOCOL(bhA, blA, it);
    if (it + 2 < 32) LOADB(bhA, blA, it+2);
    DOCOL(bhB, blB, it+1);
  }
}

// ---------------- launch ----------------

extern "C" void kernel_launch(void* const* d_in, const int* in_sizes, int n_in,
                              void* d_out, int out_size, void* d_ws, size_t ws_size,
                              hipStream_t stream){
  const float* x   = (const float*)d_in[0];
  const int*   ei  = (const int*)d_in[1];   // [2, E] int32 (jax x64 off)
  const float* W1  = (const float*)d_in[3];
  const float* b1  = (const float*)d_in[4];
  const float* W2  = (const float*)d_in[5];
  const float* b2  = (const float*)d_in[6];
  const float* Wfc = (const float*)d_in[7];
  const float* bfc = (const float*)d_in[8];
  float* out = (float*)d_out;
  const int E = in_sizes[1] / 2;

  // workspace layout (~75 MB)
  float* bufA   = (float*)d_ws;                      // 33.5 MB (reused for WT hi/lo)
  float* bufB   = bufA + (size_t)NODES*CH;           // 33.5 MB
  float* dinv   = bufB + (size_t)NODES*CH;           // 256 KB
  int*   deg    = (int*)(dinv + NODES);              // 256 KB
  int*   cstart = deg + NODES;                       // NODES+1 (+256 reserve)
  int*   cursor = cstart + NODES + 256;              // 256 KB
  int*   bsums  = cursor + NODES;                    // 1 KB
  int*   ssrc   = bsums + 256;                       // 4 MB
  __bf16* phi   = (__bf16*)(ssrc + E);               // 256 KB
  __bf16* plo   = phi + (size_t)NGRAPH*CH;           // 256 KB

  __bf16* wth = (__bf16*)bufA;                       // 16.78 MB
  __bf16* wtl = wth + (size_t)FCO*CH;                // 16.78 MB

  const int* esrc = ei;
  const int* edst = ei + E;

  k_zero2  <<<NODES/1024,  256, 0, stream>>>(deg, cursor);   // replaces 2x hipMemsetAsync
  k_degree <<<(E+255)/256, 256, 0, stream>>>(edst, deg, E);
  k_dinv   <<<NODES/256,   256, 0, stream>>>(deg, dinv);
  k_scan1  <<<NODES/256,   256, 0, stream>>>(deg, cstart, bsums);
  k_scan2  <<<1,           256, 0, stream>>>(bsums);
  k_scan3  <<<NODES/256,   256, 0, stream>>>(cstart, bsums, E);
  k_scatter<<<(E+255)/256, 256, 0, stream>>>(esrc, edst, cstart, cursor, ssrc, E);

  k_gemm128<0><<<NODES/128, 256, 0, stream>>>(x,    W1, nullptr, bufA);   // bufA = x@W1
  k_agg       <<<NODES, CH, 0, stream>>>(bufA, dinv, cstart, ssrc, bufB); // bufB = agg1
  k_gemm128<1><<<NODES/128, 256, 0, stream>>>(bufB, W2, b1,     bufA);    // bufA = relu(agg1+b1)@W2
  k_agg       <<<NODES, CH, 0, stream>>>(bufA, dinv, cstart, ssrc, bufB); // bufB = agg2

  // bufA dead -> transposed split-bf16 Wfc
  k_cvt_wfc <<<FCO/64, 256, 0, stream>>>(Wfc, wth, wtl);
  k_pool    <<<NGRAPH, CH, 0, stream>>>(bufB, b2, phi, plo);
  k_fc_mfma <<<dim3(32, NGRAPH/64), 256, 0, stream>>>(phi, plo, wth, wtl, bfc, out);
}